// Round 13
// baseline (128.343 us; speedup 1.0000x reference)
//
#include <hip/hip_runtime.h>
#include <hip/hip_bf16.h>

typedef __bf16 bf16;
typedef __attribute__((ext_vector_type(2))) __bf16 bf16x2;
typedef __attribute__((ext_vector_type(4))) __bf16 bf16x4;
typedef __attribute__((ext_vector_type(8))) __bf16 bf16x8;
typedef __attribute__((ext_vector_type(4))) float f32x4;

#define NB 4
#define NS 1024
#define NE 1024
#define NH 16
#define ND 64
#define NROT 32
#define NM (NB*NS)   // 4096 rows

// ---- async global->LDS, 16B per lane, wave-uniform LDS base ----
__device__ __forceinline__ void gload_lds16(const bf16* g, void* l) {
  __builtin_amdgcn_global_load_lds(
      (const __attribute__((address_space(1))) unsigned int*)g,
      (__attribute__((address_space(3))) unsigned int*)l,
      16, 0, 0);
}

// ---- fused prep: weight cvt (y<4), hidden cvt (y<8), rope tables (y==8) ----
struct PrepArgs {
  const float* w0; const float* w1; const float* w2; const float* w3;
  bf16* b0; bf16* b1; bf16* b2; bf16* b3;
  const float* hs; bf16* hb;
  const float* rot; float* ct; float* st;
};
__global__ void k_prep(PrepArgs a) {
  const int y = blockIdx.y;
  const int i = blockIdx.x * 256 + threadIdx.x;
  if (y < 4) {
    const float* s = (y == 0) ? a.w0 : (y == 1) ? a.w1 : (y == 2) ? a.w2 : a.w3;
    bf16* d = (y == 0) ? a.b0 : (y == 1) ? a.b1 : (y == 2) ? a.b2 : a.b3;
    float4 v = reinterpret_cast<const float4*>(s)[i];
    bf16x4 o = { (bf16)v.x, (bf16)v.y, (bf16)v.z, (bf16)v.w };
    *reinterpret_cast<bf16x4*>(d + (size_t)i * 4) = o;
  } else if (y < 8) {
    size_t off = (size_t)(y - 4) * (NM * NE / 16);   // quarter of hidden, in float4s
    float4 v = reinterpret_cast<const float4*>(a.hs)[off + i];
    bf16x4 o = { (bf16)v.x, (bf16)v.y, (bf16)v.z, (bf16)v.w };
    *reinterpret_cast<bf16x4*>(a.hb + (off + i) * 4) = o;
  } else {
    if (i < NS * NROT) {
      float v = a.rot[i];
      a.ct[i] = cosf(v);
      a.st[i] = sinf(v);
    }
  }
}

// =====================================================================
// 256x256-tile GEMM core, fine-phase schedule (R11 version — best measured).
// 512 threads / 8 waves (2M x 4N), wave C = 128x64. BK=64 double-buffered.
// Phase q: {issue 1 half-tile of K-tile t+1} + {ds_read quadrant frags} +
// {16 MFMA under setprio}, pinned by sched_barrier(0).
// Sync: 2 barriers/K-tile — phase-0 vmcnt(2)+barrier (own t-loads done,
// 2 newest fly), end-of-tile lgkmcnt(0)+barrier (retire buf reads).
// acc flat [32]: normal idx = i*4+j; SWAP idx = j*8+i.
// =====================================================================
template<bool SWAP>
__device__ __forceinline__ void gemm_core256(
    const bf16* __restrict__ A, const bf16* __restrict__ W,
    bf16* lA, bf16* lB, int m0, int n0, f32x4 (&acc)[32])
{
  const int tid = threadIdx.x;
  const int wave = tid >> 6, lane = tid & 63;
  const int wm = wave >> 2, wn = wave & 3;      // 2 m-halves x 4 n-quarters
  const int fr = lane & 15, kg = lane >> 4;
  const int lrow8 = lane >> 3, lslot = lane & 7;

  // stage one half-tile h: 0=A rows0-127, 1=A rows128-255, 2=B lo, 3=B hi
  auto stageH = [&](int kt, int c, int h) {
    const bf16* src = (h < 2) ? A : W;
    bf16* dst = (h < 2) ? lA : lB;
    const int base0 = (h < 2) ? m0 : n0;
    const int hh = h & 1;
#pragma unroll
    for (int i = 0; i < 2; ++i) {
      int chunk = hh * 16 + i * 8 + wave;       // 16 chunks per half / 8 waves
      int row = (chunk << 3) + lrow8;           // 0..255
      int slot = lslot ^ (row & 7);
      gload_lds16(src + (size_t)(base0 + row) * NE + kt + slot * 8,
                  (char*)dst + c * 32768 + chunk * 1024);
    }
  };

  // prologue: K-tile 0 fully staged
#pragma unroll
  for (int h = 0; h < 4; ++h) stageH(0, 0, h);
  asm volatile("s_waitcnt vmcnt(0)\n\ts_barrier" ::: "memory");

  constexpr int NT = NE / 64;   // 16
  bf16x8 bfrag[4][2];

  for (int t = 0; t < NT; ++t) {
    const int c = t & 1;
    const char* cA = (const char*)lA + c * 32768;
    const char* cB = (const char*)lB + c * 32768;

#pragma unroll
    for (int q = 0; q < 4; ++q) {
      // issue next-tile half q into the other buffer (free since t-1's end)
      if (t + 1 < NT) stageH((t + 1) * 64, c ^ 1, q);

      if (q == 0) {
        // publish K-tile t: each wave waits its own 8 stage-loads (issued
        // during t-1's phases); the 2 just-issued (t+1,H0) stay in flight.
        if (t > 0) {
          if (t + 1 < NT)
            asm volatile("s_waitcnt vmcnt(2)\n\ts_barrier" ::: "memory");
          else
            asm volatile("s_waitcnt vmcnt(0)\n\ts_barrier" ::: "memory");
        }
        // hoist B fragments for the whole K-tile (8 reads)
#pragma unroll
        for (int j = 0; j < 4; ++j) {
          int rb = wn * 64 + j * 16 + fr;
#pragma unroll
          for (int kk = 0; kk < 2; ++kk)
            bfrag[j][kk] = *reinterpret_cast<const bf16x8*>(
                cB + rb * 128 + (((kg + 4 * kk) ^ (rb & 7)) << 4));
        }
      }

      // A fragments for this quadrant (4 reads)
      bf16x8 af[2][2];
#pragma unroll
      for (int u = 0; u < 2; ++u) {
        int ra = wm * 128 + (2 * q + u) * 16 + fr;
#pragma unroll
        for (int kk = 0; kk < 2; ++kk)
          af[u][kk] = *reinterpret_cast<const bf16x8*>(
              cA + ra * 128 + (((kg + 4 * kk) ^ (ra & 7)) << 4));
      }

      __builtin_amdgcn_sched_barrier(0);
      __builtin_amdgcn_s_setprio(1);
#pragma unroll
      for (int kk = 0; kk < 2; ++kk)
#pragma unroll
        for (int u = 0; u < 2; ++u)
#pragma unroll
          for (int j = 0; j < 4; ++j) {
            const int i = 2 * q + u;
            if constexpr (SWAP)
              acc[j * 8 + i] = __builtin_amdgcn_mfma_f32_16x16x32_bf16(
                  bfrag[j][kk], af[u][kk], acc[j * 8 + i], 0, 0, 0);
            else
              acc[i * 4 + j] = __builtin_amdgcn_mfma_f32_16x16x32_bf16(
                  af[u][kk], bfrag[j][kk], acc[i * 4 + j], 0, 0, 0);
          }
      __builtin_amdgcn_s_setprio(0);
      __builtin_amdgcn_sched_barrier(0);
    }

    // end of K-tile: retire all reads of buf c before t+2 overwrites it
    asm volatile("s_waitcnt lgkmcnt(0)\n\ts_barrier" ::: "memory");
  }
}

// ---- fused projections + rope, 256^2 tiles: z=0 Q, z=1 K, z=2 V-transposed ----
__global__ __launch_bounds__(512) void k_proj(
    const bf16* __restrict__ A, const bf16* __restrict__ Wq, const bf16* __restrict__ Wk,
    const bf16* __restrict__ Wv, bf16* __restrict__ Oq, bf16* __restrict__ Ok,
    bf16* __restrict__ vt, const float* __restrict__ ct, const float* __restrict__ st)
{
  __shared__ bf16 lA[2 * 256 * 64];
  __shared__ bf16 lB[2 * 256 * 64];
  const int z = blockIdx.z;
  const int m0 = blockIdx.x * 256, n0 = blockIdx.y * 256;
  const int tid = threadIdx.x;
  const int wave = tid >> 6, lane = tid & 63;
  const int wm = wave >> 2, wn = wave & 3;
  const int fr = lane & 15, kg = lane >> 4;

  f32x4 acc[32] = {};

  if (z == 2) {
    // V projection, transposed output vt[bh][d][s]; acc[j*8+i]: rows=e, cols=s
    gemm_core256<true>(A, Wv, lA, lB, m0, n0, acc);

    const int b = m0 >> 10;                     // m0 256-aligned, within one b
    const int h = (n0 + wn * 64) >> 6;          // wave's 64 e-cols = one head
    bf16* vtb = vt + ((size_t)(b * 16 + h)) * ND * NS;
#pragma unroll
    for (int i = 0; i < 8; ++i) {
      int sl = (m0 & (NS - 1)) + wm * 128 + i * 16 + fr;
#pragma unroll
      for (int r = 0; r < 4; ++r) {
        int dbase = kg * 4 + r;
        float x0 = acc[0 * 8 + i][r];           // d = dbase
        float x1 = acc[1 * 8 + i][r];           // d = 16 + dbase
        float c0 = ct[sl * NROT + dbase],      sn0 = st[sl * NROT + dbase];
        float c1 = ct[sl * NROT + 16 + dbase], sn1 = st[sl * NROT + 16 + dbase];
        float y0 = x0 * c0 - x1 * sn0;
        float y1 = x1 * c1 + x0 * sn1;
        vtb[(size_t)(dbase)      * NS + sl] = (bf16)y0;
        vtb[(size_t)(16 + dbase) * NS + sl] = (bf16)y1;
        vtb[(size_t)(32 + dbase) * NS + sl] = (bf16)acc[2 * 8 + i][r];
        vtb[(size_t)(48 + dbase) * NS + sl] = (bf16)acc[3 * 8 + i][r];
      }
    }
  } else {
    const bf16* W = (z == 0) ? Wq : Wk;
    bf16* Og = (z == 0) ? Oq : Ok;
    // q carries D^-0.5 * log2(e) so softmax runs in exp2 domain
    const float scale = (z == 0) ? 0.125f * 1.44269504f : 1.0f;

    gemm_core256<false>(A, W, lA, lB, m0, n0, acc);

#pragma unroll
    for (int i = 0; i < 8; ++i) {
      int rowbase = m0 + wm * 128 + i * 16 + kg * 4;
#pragma unroll
      for (int r = 0; r < 4; ++r) {
        int gm = rowbase + r;
        int s = gm & (NS - 1);
        float x0 = acc[i * 4 + 0][r] * scale;
        float x1 = acc[i * 4 + 1][r] * scale;
        float c0 = ct[s * NROT + fr],      sn0 = st[s * NROT + fr];
        float c1 = ct[s * NROT + 16 + fr], sn1 = st[s * NROT + 16 + fr];
        float y0 = x0 * c0 - x1 * sn0;
        float y1 = x1 * c1 + x0 * sn1;
        size_t rb = (size_t)gm * NE + n0 + wn * 64;
        Og[rb + 0 * 16 + fr] = (bf16)y0;
        Og[rb + 1 * 16 + fr] = (bf16)y1;
        Og[rb + 2 * 16 + fr] = (bf16)(acc[i * 4 + 2][r] * scale);
        Og[rb + 3 * 16 + fr] = (bf16)(acc[i * 4 + 3][r] * scale);
      }
    }
  }
}

// ---- small GEMM core (BK=32 dbuf, counted vmcnt) for the O projection ----
template<int BM, int BN>
__device__ __forceinline__ void gemm_core(
    const bf16* __restrict__ A, const bf16* __restrict__ W,
    bf16* lA, bf16* lB, int m0, int n0, f32x4 (&acc)[BM/32][BN/32])
{
  const int tid = threadIdx.x;
  const int wave = tid >> 6, lane = tid & 63;
  const int wm = wave >> 1, wn = wave & 1;
  const int fr = lane & 15, kg = lane >> 4;

  const int sline = lane >> 3;
  const int lsl   = (lane & 7) ^ sline;
  const int srow  = 2 * sline + (lsl >> 2);
  const int skcol = (lsl & 3) * 8;
  constexpr int ACH = BM / 64;
  constexpr int BCH = BN / 64;
  constexpr int NSTAGE = ACH + BCH;

  auto stage = [&](int kt, int c) {
#pragma unroll
    for (int i = 0; i < ACH; ++i) {
      int chunk = i * 4 + wave;
      gload_lds16(A + (size_t)(m0 + chunk * 16 + srow) * NE + kt + skcol,
                  (char*)lA + c * (BM * 64) + chunk * 1024);
    }
#pragma unroll
    for (int i = 0; i < BCH; ++i) {
      int chunk = i * 4 + wave;
      gload_lds16(W + (size_t)(n0 + chunk * 16 + srow) * NE + kt + skcol,
                  (char*)lB + c * (BN * 64) + chunk * 1024);
    }
  };

  auto foff = [&](int ra) {
    return (ra >> 1) * 128 + (((((ra & 1) << 2) + kg) ^ ((ra >> 1) & 7)) << 4);
  };

  stage(0, 0);

  for (int kt = 0; kt < NE / 32; ++kt) {
    const int c = kt & 1;
    if (kt + 1 < NE / 32) {
      stage((kt + 1) * 32, c ^ 1);
      asm volatile("s_waitcnt vmcnt(%0)\n\ts_barrier" :: "n"(NSTAGE) : "memory");
    } else {
      asm volatile("s_waitcnt vmcnt(0)\n\ts_barrier" ::: "memory");
    }

    const char* cA = (const char*)lA + c * (BM * 64);
    const char* cB = (const char*)lB + c * (BN * 64);
    bf16x8 af[BM / 32], bfr[BN / 32];
#pragma unroll
    for (int i = 0; i < BM / 32; ++i)
      af[i] = *reinterpret_cast<const bf16x8*>(cA + foff(wm * (BM / 2) + i * 16 + fr));
#pragma unroll
    for (int j = 0; j < BN / 32; ++j)
      bfr[j] = *reinterpret_cast<const bf16x8*>(cB + foff(wn * (BN / 2) + j * 16 + fr));
#pragma unroll
    for (int i = 0; i < BM / 32; ++i)
#pragma unroll
      for (int j = 0; j < BN / 32; ++j)
        acc[i][j] = __builtin_amdgcn_mfma_f32_16x16x32_bf16(af[i], bfr[j], acc[i][j], 0, 0, 0);
    asm volatile("s_waitcnt lgkmcnt(0)\n\ts_barrier" ::: "memory");
  }
}

// ---- output projection + bias (64x128 tile) ----
__global__ __launch_bounds__(256) void k_gemm_o(
    const bf16* __restrict__ A, const bf16* __restrict__ W, float* __restrict__ Og,
    const float* __restrict__ bias)
{
  __shared__ bf16 lA[2 * 64 * 32];
  __shared__ bf16 lB[2 * 128 * 32];
  const int m0 = blockIdx.x * 64, n0 = blockIdx.y * 128;
  f32x4 acc[2][4] = {};
  gemm_core<64, 128>(A, W, lA, lB, m0, n0, acc);

  const int tid = threadIdx.x;
  const int wave = tid >> 6, lane = tid & 63;
  const int wm = wave >> 1, wn = wave & 1;
  const int fr = lane & 15, kg = lane >> 4;
#pragma unroll
  for (int i = 0; i < 2; ++i)
#pragma unroll
    for (int j = 0; j < 4; ++j) {
      int gc = n0 + wn * 64 + j * 16 + fr;
      float bv = bias[gc];
#pragma unroll
      for (int r = 0; r < 4; ++r) {
        int gm = m0 + wm * 32 + i * 16 + kg * 4 + r;
        Og[(size_t)gm * NE + gc] = acc[i][j][r] + bv;
      }
    }
}

// ---- causal flash attention, swapped-QK^T in-lane softmax, 1 barrier/tile ----
// Single 64-row q-tile per block; 4 waves x 16 q-rows. kv tiles of 64.
// lK double-buffered (only cross-wave shared data); lP per-wave private
// (no barrier needed); V^T read directly from global (L2-resident) as PV
// B-fragments. PV's own global loads drain the older K-stage loads (vmcnt
// is issue-ordered), so the single end-of-tile barrier publishes K(t+1).
// Q,K,O: [NM][NE] bf16 (head h at cols h*64); VT: [bh][d][s].
__global__ __launch_bounds__(256) void k_attn(
    const bf16* __restrict__ Q, const bf16* __restrict__ K,
    const bf16* __restrict__ VT, bf16* __restrict__ O)
{
  __shared__ bf16 lK[2][64 * 64];
  __shared__ bf16 lP[4][16 * 68];
  const int tid = threadIdx.x;
  const int wave = tid >> 6, lane = tid & 63;
  const int fr = lane & 15, kg = lane >> 4;

  // grid (8,128): x = bh&7 (XCD affinity via linear%8); y = (15-qt)*8 + bhHi
  const int qt = 15 - (blockIdx.y >> 3);          // descending: long blocks first
  const int bh = blockIdx.x | ((blockIdx.y & 7) << 3);
  const int b = bh >> 4, h = bh & 15;
  const int nt = qt + 1;
  const bf16* Qb  = Q + (size_t)b * NS * NE + h * 64;
  const bf16* Kb  = K + (size_t)b * NS * NE + h * 64;
  const bf16* VTb = VT + (size_t)bh * ND * NS;
  bf16* Ob = O + (size_t)b * NS * NE + h * 64;

  const int qrow0 = qt * 64 + wave * 16;          // this wave's first q row

  // Q fragment (B-operand): lane (fr,kg) supplies q-col = qrow0+fr, k = kk*32+kg*8
  bf16x8 qf[2];
#pragma unroll
  for (int kk = 0; kk < 2; ++kk)
    qf[kk] = *reinterpret_cast<const bf16x8*>(
        Qb + (size_t)(qrow0 + fr) * NE + kk * 32 + kg * 8);

  // K staging: per-lane invariant addresses (row&7 == lane>>3 for both chunks)
  const int srow = lane >> 3;                     // 0..7
  const int sslot = (lane & 7) ^ srow;            // swizzled 16B slot
  const int r0 = wave * 8 + srow;                 // rows for chunk wave
  const int r1 = (wave + 4) * 8 + srow;           // rows for chunk wave+4
  const bf16* kA0 = Kb + (size_t)r0 * NE + sslot * 8;
  const bf16* kA1 = Kb + (size_t)r1 * NE + sslot * 8;
  char* ldsKa[2] = { (char*)lK[0] + wave * 1024, (char*)lK[1] + wave * 1024 };
  char* ldsKb[2] = { (char*)lK[0] + (wave + 4) * 1024, (char*)lK[1] + (wave + 4) * 1024 };

  float m_ = -3.0e38f, l_ = 0.f;
  f32x4 oacc[4] = {};

  // prologue: K(0) -> lK[0]
  gload_lds16(kA0, ldsKa[0]);
  gload_lds16(kA1, ldsKb[0]);
  __syncthreads();

  for (int t = 0; t < nt; ++t) {
    const int c = t & 1;
    const int kv0 = t * 64;
    // issue K(t+1) early; drains implicitly under PV's newer global loads.
    if (t + 1 < nt) {
      gload_lds16(kA0 + (size_t)(t + 1) * 64 * NE, ldsKa[c ^ 1]);
      gload_lds16(kA1 + (size_t)(t + 1) * 64 * NE, ldsKb[c ^ 1]);
    }

    // QK^T swapped: sacc[j][r] = S[kv = 16j+4kg+r][q = qrow0+fr]
    const bf16* lKc = lK[c];
    f32x4 sacc[4] = {};
    __builtin_amdgcn_s_setprio(1);
#pragma unroll
    for (int kk = 0; kk < 2; ++kk)
#pragma unroll
      for (int j = 0; j < 4; ++j) {
        int rc = j * 16 + fr;
        bf16x8 kf = *reinterpret_cast<const bf16x8*>(
            lKc + rc * 64 + (((kg + 4 * kk) ^ (rc & 7)) << 3));
        sacc[j] = __builtin_amdgcn_mfma_f32_16x16x32_bf16(kf, qf[kk], sacc[j], 0, 0, 0);
      }
    __builtin_amdgcn_s_setprio(0);

    if (t == qt) {   // diagonal tile: mask kv_local > wave*16 + fr
      const int ql = wave * 16 + fr;
#pragma unroll
      for (int j = 0; j < 4; ++j)
#pragma unroll
        for (int r = 0; r < 4; ++r)
          if (16 * j + 4 * kg + r > ql) sacc[j][r] = -3.0e38f;
    }

    // in-lane row max (16 values) + cross-kg reduce
    float m4 = fmaxf(fmaxf(fmaxf(sacc[0][0], sacc[0][1]), fmaxf(sacc[0][2], sacc[0][3])),
                     fmaxf(fmaxf(sacc[1][0], sacc[1][1]), fmaxf(sacc[1][2], sacc[1][3])));
    m4 = fmaxf(m4, fmaxf(fmaxf(fmaxf(sacc[2][0], sacc[2][1]), fmaxf(sacc[2][2], sacc[2][3])),
                         fmaxf(fmaxf(sacc[3][0], sacc[3][1]), fmaxf(sacc[3][2], sacc[3][3]))));
    m4 = fmaxf(m4, __shfl_xor(m4, 16));
    m4 = fmaxf(m4, __shfl_xor(m4, 32));

    // defer-max (THR=8): rescale only when the max grew materially
    if (!__all(m4 - m_ <= 8.0f)) {
      float nm = fmaxf(m_, m4);
      float corr = exp2f(m_ - nm);
      m_ = nm;
      l_ *= corr;
#pragma unroll
      for (int r = 0; r < 4; ++r) {
        float cr = __shfl(corr, kg * 4 + r);   // corr lives at lanes fr==q
#pragma unroll
        for (int df = 0; df < 4; ++df) oacc[df][r] *= cr;
      }
    }

    // P = exp2(S - m_), pack bf16x4 (kv-consecutive), one b64 write per j
    float ps = 0.f;
#pragma unroll
    for (int j = 0; j < 4; ++j) {
      float p0 = exp2f(sacc[j][0] - m_);
      float p1 = exp2f(sacc[j][1] - m_);
      float p2 = exp2f(sacc[j][2] - m_);
      float p3 = exp2f(sacc[j][3] - m_);
      ps += (p0 + p1) + (p2 + p3);
      bf16x4 pp = { (bf16)p0, (bf16)p1, (bf16)p2, (bf16)p3 };
      *reinterpret_cast<bf16x4*>(&lP[wave][fr * 68 + j * 16 + kg * 4]) = pp;
    }
    ps += __shfl_xor(ps, 16);
    ps += __shfl_xor(ps, 32);
    l_ += ps;

    // PV: A = P rows (lP is wave-private: wave-internal lgkm ordering only),
    // B = V^T rows direct from global (L2-hit).
    __builtin_amdgcn_s_setprio(1);
#pragma unroll
    for (int ks = 0; ks < 2; ++ks) {
      bf16x8 pf = *reinterpret_cast<const bf16x8*>(&lP[wave][fr * 68 + ks * 32 + kg * 8]);
#pragma unroll
      for (int df = 0; df < 4; ++df) {
        bf16x8 vf = *reinterpret_cast<const bf16x8*>(
            VTb + (size_t)(df * 16 + fr) * NS + kv0 + ks * 32 + kg * 8);
        oacc[df] = __builtin_amdgcn_mfma_f32_16x16x32_bf16(pf, vf, oacc[df], 0, 0, 0);
      }
    }
    __builtin_amdgcn_s_setprio(0);

    __syncthreads();   // publishes K(t+1) (already drained by PV's loads);
                       // lK[c] reads retired pre-MFMA -> safe to overwrite next iter
  }

  // epilogue: O[q = qrow0 + kg*4 + r][d = df*16 + fr], divide by l (at lanes fr==q)
  float linv[4];
#pragma unroll
  for (int r = 0; r < 4; ++r) linv[r] = 1.0f / __shfl(l_, kg * 4 + r);
#pragma unroll
  for (int df = 0; df < 4; ++df)
#pragma unroll
    for (int r = 0; r < 4; ++r)
      Ob[(size_t)(qrow0 + kg * 4 + r) * NE + df * 16 + fr] = (bf16)(oacc[df][r] * linv[r]);
}

extern "C" void kernel_launch(void* const* d_in, const int* in_sizes, int n_in,
                              void* d_out, int out_size, void* d_ws, size_t ws_size,
                              hipStream_t stream) {
  const float* hs  = (const float*)d_in[0];
  const float* rot = (const float*)d_in[1];
  const float* qw  = (const float*)d_in[2];
  const float* kw  = (const float*)d_in[3];
  const float* vw  = (const float*)d_in[4];
  const float* ow  = (const float*)d_in[5];
  const float* obb = (const float*)d_in[6];
  float* out = (float*)d_out;

  char* ws = (char*)d_ws;
  size_t off = 0;
  bf16* hb  = (bf16*)(ws + off); off += (size_t)NM * NE * 2;
  bf16* wqb = (bf16*)(ws + off); off += (size_t)NE * NE * 2;
  bf16* wkb = (bf16*)(ws + off); off += (size_t)NE * NE * 2;
  bf16* wvb = (bf16*)(ws + off); off += (size_t)NE * NE * 2;
  bf16* wob = (bf16*)(ws + off); off += (size_t)NE * NE * 2;
  bf16* qb  = (bf16*)(ws + off); off += (size_t)NM * NE * 2;
  bf16* kb  = (bf16*)(ws + off); off += (size_t)NM * NE * 2;
  bf16* vt  = (bf16*)(ws + off); off += (size_t)NM * NE * 2;   // [bh][d][s]
  float* ct = (float*)(ws + off); off += (size_t)NS * NROT * 4;
  float* st = (float*)(ws + off); off += (size_t)NS * NROT * 4;
  bf16* aob = hb;   // hidden bf16 is dead after projections

  // fused prep (one dispatch): 4 weight-cvt slices, 4 hidden-cvt slices, tables
  PrepArgs pa = { qw, kw, vw, ow, wqb, wkb, wvb, wob, hs, hb, rot, ct, st };
  k_prep<<<dim3(NE * NE / 4 / 256, 9), dim3(256), 0, stream>>>(pa);

  // fused Q/K/VT projections + rope (256^2 tiles, fine-phase schedule)
  k_proj<<<dim3(NM / 256, NE / 256, 3), dim3(512), 0, stream>>>(
      hb, wqb, wkb, wvb, qb, kb, vt, ct, st);

  // causal flash attention (single-tile blocks, qt-descending, 1024 blocks)
  k_attn<<<dim3(8, 128), dim3(256), 0, stream>>>(qb, kb, vt, aob);

  // output projection + bias
  k_gemm_o<<<dim3(NM / 64, NE / 128), dim3(256), 0, stream>>>(aob, wob, out, obb);

  (void)in_sizes; (void)n_in; (void)out_size; (void)ws_size;
}

// Round 14
// 96.609 us; speedup vs baseline: 1.3285x; 1.3285x over previous
//
#include <hip/hip_runtime.h>
#include <hip/hip_bf16.h>

typedef __bf16 bf16;
typedef __attribute__((ext_vector_type(2))) __bf16 bf16x2;
typedef __attribute__((ext_vector_type(4))) __bf16 bf16x4;
typedef __attribute__((ext_vector_type(8))) __bf16 bf16x8;
typedef __attribute__((ext_vector_type(4))) float f32x4;

#define NB 4
#define NS 1024
#define NE 1024
#define NH 16
#define ND 64
#define NROT 32
#define NM (NB*NS)   // 4096 rows

// ---- async global->LDS, 16B per lane, wave-uniform LDS base ----
__device__ __forceinline__ void gload_lds16(const bf16* g, void* l) {
  __builtin_amdgcn_global_load_lds(
      (const __attribute__((address_space(1))) unsigned int*)g,
      (__attribute__((address_space(3))) unsigned int*)l,
      16, 0, 0);
}

// ---- fused prep: weight cvt (y<4), hidden cvt (y<8), rope tables (y==8) ----
struct PrepArgs {
  const float* w0; const float* w1; const float* w2; const float* w3;
  bf16* b0; bf16* b1; bf16* b2; bf16* b3;
  const float* hs; bf16* hb;
  const float* rot; float* ct; float* st;
};
__global__ void k_prep(PrepArgs a) {
  const int y = blockIdx.y;
  const int i = blockIdx.x * 256 + threadIdx.x;
  if (y < 4) {
    const float* s = (y == 0) ? a.w0 : (y == 1) ? a.w1 : (y == 2) ? a.w2 : a.w3;
    bf16* d = (y == 0) ? a.b0 : (y == 1) ? a.b1 : (y == 2) ? a.b2 : a.b3;
    float4 v = reinterpret_cast<const float4*>(s)[i];
    bf16x4 o = { (bf16)v.x, (bf16)v.y, (bf16)v.z, (bf16)v.w };
    *reinterpret_cast<bf16x4*>(d + (size_t)i * 4) = o;
  } else if (y < 8) {
    size_t off = (size_t)(y - 4) * (NM * NE / 16);   // quarter of hidden, in float4s
    float4 v = reinterpret_cast<const float4*>(a.hs)[off + i];
    bf16x4 o = { (bf16)v.x, (bf16)v.y, (bf16)v.z, (bf16)v.w };
    *reinterpret_cast<bf16x4*>(a.hb + (off + i) * 4) = o;
  } else {
    if (i < NS * NROT) {
      float v = a.rot[i];
      a.ct[i] = cosf(v);
      a.st[i] = sinf(v);
    }
  }
}

// =====================================================================
// 256x256-tile GEMM core, fine-phase schedule (R11 — best measured proj).
// 512 threads / 8 waves (2M x 4N), wave C = 128x64. BK=64 double-buffered.
// =====================================================================
template<bool SWAP>
__device__ __forceinline__ void gemm_core256(
    const bf16* __restrict__ A, const bf16* __restrict__ W,
    bf16* lA, bf16* lB, int m0, int n0, f32x4 (&acc)[32])
{
  const int tid = threadIdx.x;
  const int wave = tid >> 6, lane = tid & 63;
  const int wm = wave >> 2, wn = wave & 3;      // 2 m-halves x 4 n-quarters
  const int fr = lane & 15, kg = lane >> 4;
  const int lrow8 = lane >> 3, lslot = lane & 7;

  // stage one half-tile h: 0=A rows0-127, 1=A rows128-255, 2=B lo, 3=B hi
  auto stageH = [&](int kt, int c, int h) {
    const bf16* src = (h < 2) ? A : W;
    bf16* dst = (h < 2) ? lA : lB;
    const int base0 = (h < 2) ? m0 : n0;
    const int hh = h & 1;
#pragma unroll
    for (int i = 0; i < 2; ++i) {
      int chunk = hh * 16 + i * 8 + wave;       // 16 chunks per half / 8 waves
      int row = (chunk << 3) + lrow8;           // 0..255
      int slot = lslot ^ (row & 7);
      gload_lds16(src + (size_t)(base0 + row) * NE + kt + slot * 8,
                  (char*)dst + c * 32768 + chunk * 1024);
    }
  };

  // prologue: K-tile 0 fully staged
#pragma unroll
  for (int h = 0; h < 4; ++h) stageH(0, 0, h);
  asm volatile("s_waitcnt vmcnt(0)\n\ts_barrier" ::: "memory");

  constexpr int NT = NE / 64;   // 16
  bf16x8 bfrag[4][2];

  for (int t = 0; t < NT; ++t) {
    const int c = t & 1;
    const char* cA = (const char*)lA + c * 32768;
    const char* cB = (const char*)lB + c * 32768;

#pragma unroll
    for (int q = 0; q < 4; ++q) {
      if (t + 1 < NT) stageH((t + 1) * 64, c ^ 1, q);

      if (q == 0) {
        if (t > 0) {
          if (t + 1 < NT)
            asm volatile("s_waitcnt vmcnt(2)\n\ts_barrier" ::: "memory");
          else
            asm volatile("s_waitcnt vmcnt(0)\n\ts_barrier" ::: "memory");
        }
#pragma unroll
        for (int j = 0; j < 4; ++j) {
          int rb = wn * 64 + j * 16 + fr;
#pragma unroll
          for (int kk = 0; kk < 2; ++kk)
            bfrag[j][kk] = *reinterpret_cast<const bf16x8*>(
                cB + rb * 128 + (((kg + 4 * kk) ^ (rb & 7)) << 4));
        }
      }

      bf16x8 af[2][2];
#pragma unroll
      for (int u = 0; u < 2; ++u) {
        int ra = wm * 128 + (2 * q + u) * 16 + fr;
#pragma unroll
        for (int kk = 0; kk < 2; ++kk)
          af[u][kk] = *reinterpret_cast<const bf16x8*>(
              cA + ra * 128 + (((kg + 4 * kk) ^ (ra & 7)) << 4));
      }

      __builtin_amdgcn_sched_barrier(0);
      __builtin_amdgcn_s_setprio(1);
#pragma unroll
      for (int kk = 0; kk < 2; ++kk)
#pragma unroll
        for (int u = 0; u < 2; ++u)
#pragma unroll
          for (int j = 0; j < 4; ++j) {
            const int i = 2 * q + u;
            if constexpr (SWAP)
              acc[j * 8 + i] = __builtin_amdgcn_mfma_f32_16x16x32_bf16(
                  bfrag[j][kk], af[u][kk], acc[j * 8 + i], 0, 0, 0);
            else
              acc[i * 4 + j] = __builtin_amdgcn_mfma_f32_16x16x32_bf16(
                  af[u][kk], bfrag[j][kk], acc[i * 4 + j], 0, 0, 0);
          }
      __builtin_amdgcn_s_setprio(0);
      __builtin_amdgcn_sched_barrier(0);
    }

    asm volatile("s_waitcnt lgkmcnt(0)\n\ts_barrier" ::: "memory");
  }
}

// ---- fused projections + rope, 256^2 tiles: z=0 Q, z=1 K, z=2 V-transposed ----
__global__ __launch_bounds__(512) void k_proj(
    const bf16* __restrict__ A, const bf16* __restrict__ Wq, const bf16* __restrict__ Wk,
    const bf16* __restrict__ Wv, bf16* __restrict__ Oq, bf16* __restrict__ Ok,
    bf16* __restrict__ vt, const float* __restrict__ ct, const float* __restrict__ st)
{
  __shared__ bf16 lA[2 * 256 * 64];
  __shared__ bf16 lB[2 * 256 * 64];
  const int z = blockIdx.z;
  const int m0 = blockIdx.x * 256, n0 = blockIdx.y * 256;
  const int tid = threadIdx.x;
  const int wave = tid >> 6, lane = tid & 63;
  const int wm = wave >> 2, wn = wave & 3;
  const int fr = lane & 15, kg = lane >> 4;

  f32x4 acc[32] = {};

  if (z == 2) {
    gemm_core256<true>(A, Wv, lA, lB, m0, n0, acc);

    const int b = m0 >> 10;
    const int h = (n0 + wn * 64) >> 6;
    bf16* vtb = vt + ((size_t)(b * 16 + h)) * ND * NS;
#pragma unroll
    for (int i = 0; i < 8; ++i) {
      int sl = (m0 & (NS - 1)) + wm * 128 + i * 16 + fr;
#pragma unroll
      for (int r = 0; r < 4; ++r) {
        int dbase = kg * 4 + r;
        float x0 = acc[0 * 8 + i][r];
        float x1 = acc[1 * 8 + i][r];
        float c0 = ct[sl * NROT + dbase],      sn0 = st[sl * NROT + dbase];
        float c1 = ct[sl * NROT + 16 + dbase], sn1 = st[sl * NROT + 16 + dbase];
        float y0 = x0 * c0 - x1 * sn0;
        float y1 = x1 * c1 + x0 * sn1;
        vtb[(size_t)(dbase)      * NS + sl] = (bf16)y0;
        vtb[(size_t)(16 + dbase) * NS + sl] = (bf16)y1;
        vtb[(size_t)(32 + dbase) * NS + sl] = (bf16)acc[2 * 8 + i][r];
        vtb[(size_t)(48 + dbase) * NS + sl] = (bf16)acc[3 * 8 + i][r];
      }
    }
  } else {
    const bf16* W = (z == 0) ? Wq : Wk;
    bf16* Og = (z == 0) ? Oq : Ok;
    const float scale = (z == 0) ? 0.125f * 1.44269504f : 1.0f;

    gemm_core256<false>(A, W, lA, lB, m0, n0, acc);

#pragma unroll
    for (int i = 0; i < 8; ++i) {
      int rowbase = m0 + wm * 128 + i * 16 + kg * 4;
#pragma unroll
      for (int r = 0; r < 4; ++r) {
        int gm = rowbase + r;
        int s = gm & (NS - 1);
        float x0 = acc[i * 4 + 0][r] * scale;
        float x1 = acc[i * 4 + 1][r] * scale;
        float c0 = ct[s * NROT + fr],      sn0 = st[s * NROT + fr];
        float c1 = ct[s * NROT + 16 + fr], sn1 = st[s * NROT + 16 + fr];
        float y0 = x0 * c0 - x1 * sn0;
        float y1 = x1 * c1 + x0 * sn1;
        size_t rb = (size_t)gm * NE + n0 + wn * 64;
        Og[rb + 0 * 16 + fr] = (bf16)y0;
        Og[rb + 1 * 16 + fr] = (bf16)y1;
        Og[rb + 2 * 16 + fr] = (bf16)(acc[i * 4 + 2][r] * scale);
        Og[rb + 3 * 16 + fr] = (bf16)(acc[i * 4 + 3][r] * scale);
      }
    }
  }
}

// ---- output projection + bias: R6 simple single-buffered core (best-total cfg) ----
__global__ __launch_bounds__(256) void k_gemm_o(
    const bf16* __restrict__ A, const bf16* __restrict__ W, float* __restrict__ Og,
    const float* __restrict__ bias)
{
  __shared__ bf16 lA[64 * 64];
  __shared__ bf16 lB[128 * 64];
  const int m0 = blockIdx.x * 64, n0 = blockIdx.y * 128;
  const int tid = threadIdx.x;
  const int wave = tid >> 6, lane = tid & 63;
  const int wm = wave >> 1, wn = wave & 1;
  const int fr = lane & 15, kg = lane >> 4;
  const int lrow8 = lane >> 3, lslot = lane & 7;

  f32x4 acc[2][4] = {};

  for (int kt = 0; kt < NE; kt += 64) {
#pragma unroll
    for (int i = 0; i < 2; ++i) {
      int chunk = i * 4 + wave;
      int row = (chunk << 3) + lrow8;
      int slot = lslot ^ (row & 7);
      gload_lds16(A + (size_t)(m0 + row) * NE + kt + slot * 8, (char*)lA + chunk * 1024);
    }
#pragma unroll
    for (int i = 0; i < 4; ++i) {
      int chunk = i * 4 + wave;
      int row = (chunk << 3) + lrow8;
      int slot = lslot ^ (row & 7);
      gload_lds16(W + (size_t)(n0 + row) * NE + kt + slot * 8, (char*)lB + chunk * 1024);
    }
    __syncthreads();
#pragma unroll
    for (int kk = 0; kk < 2; ++kk) {
      bf16x8 af[2], bfr[4];
#pragma unroll
      for (int i = 0; i < 2; ++i) {
        int ra = wm * 32 + i * 16 + fr;
        af[i] = *reinterpret_cast<const bf16x8*>(lA + ra * 64 + (((kg + 4 * kk) ^ (ra & 7)) << 3));
      }
#pragma unroll
      for (int j = 0; j < 4; ++j) {
        int rb = wn * 64 + j * 16 + fr;
        bfr[j] = *reinterpret_cast<const bf16x8*>(lB + rb * 64 + (((kg + 4 * kk) ^ (rb & 7)) << 3));
      }
#pragma unroll
      for (int i = 0; i < 2; ++i)
#pragma unroll
        for (int j = 0; j < 4; ++j)
          acc[i][j] = __builtin_amdgcn_mfma_f32_16x16x32_bf16(af[i], bfr[j], acc[i][j], 0, 0, 0);
    }
    __syncthreads();
  }

#pragma unroll
  for (int i = 0; i < 2; ++i)
#pragma unroll
    for (int j = 0; j < 4; ++j) {
      int gc = n0 + wn * 64 + j * 16 + fr;
      float bv = bias[gc];
#pragma unroll
      for (int r = 0; r < 4; ++r) {
        int gm = m0 + wm * 32 + i * 16 + kg * 4 + r;
        Og[(size_t)gm * NE + gc] = acc[i][j][r] + bv;
      }
    }
}

// ---- causal flash attention (R12 version — proven): swapped-QK^T in-lane
// softmax; lK double-buffered, lVT single-buffered, both next-loads issued at
// iter top; 2 barriers/tile. Q,K,O: [NM][NE] bf16; VT: [bh][d][s].
__global__ __launch_bounds__(256) void k_attn(
    const bf16* __restrict__ Q, const bf16* __restrict__ K,
    const bf16* __restrict__ VT, bf16* __restrict__ O)
{
  __shared__ bf16 lK[2][64 * 64];
  __shared__ bf16 lVT[64 * 64];
  __shared__ bf16 lP[4][16 * 68];
  const int tid = threadIdx.x;
  const int wave = tid >> 6, lane = tid & 63;
  const int fr = lane & 15, kg = lane >> 4;

  const int qt = 15 - (blockIdx.y >> 3);          // descending: long blocks first
  const int bh = blockIdx.x | ((blockIdx.y & 7) << 3);
  const int b = bh >> 4, h = bh & 15;
  const int nt = qt + 1;
  const bf16* Qb  = Q + (size_t)b * NS * NE + h * 64;
  const bf16* Kb  = K + (size_t)b * NS * NE + h * 64;
  const bf16* VTb = VT + (size_t)bh * ND * NS;
  bf16* Ob = O + (size_t)b * NS * NE + h * 64;

  const int qrow0 = qt * 64 + wave * 16;

  bf16x8 qf[2];
#pragma unroll
  for (int kk = 0; kk < 2; ++kk)
    qf[kk] = *reinterpret_cast<const bf16x8*>(
        Qb + (size_t)(qrow0 + fr) * NE + kk * 32 + kg * 8);

  const int srow = lane >> 3;
  const int sslot = (lane & 7) ^ srow;
  const int r0 = wave * 8 + srow;
  const int r1 = (wave + 4) * 8 + srow;
  const bf16* kA0 = Kb + (size_t)r0 * NE + sslot * 8;
  const bf16* kA1 = Kb + (size_t)r1 * NE + sslot * 8;
  const bf16* vA0 = VTb + (size_t)r0 * NS + sslot * 8;
  const bf16* vA1 = VTb + (size_t)r1 * NS + sslot * 8;
  char* ldsKa[2] = { (char*)lK[0] + wave * 1024, (char*)lK[1] + wave * 1024 };
  char* ldsKb[2] = { (char*)lK[0] + (wave + 4) * 1024, (char*)lK[1] + (wave + 4) * 1024 };
  char* ldsVa  = (char*)lVT + wave * 1024;
  char* ldsVb  = (char*)lVT + (wave + 4) * 1024;

  float m_ = -3.0e38f, l_ = 0.f;
  f32x4 oacc[4] = {};

  gload_lds16(kA0, ldsKa[0]);
  gload_lds16(kA1, ldsKb[0]);
  __syncthreads();

  for (int t = 0; t < nt; ++t) {
    const int c = t & 1;
    gload_lds16(vA0 + t * 64, ldsVa);
    gload_lds16(vA1 + t * 64, ldsVb);
    if (t + 1 < nt) {
      gload_lds16(kA0 + (size_t)(t + 1) * 64 * NE, ldsKa[c ^ 1]);
      gload_lds16(kA1 + (size_t)(t + 1) * 64 * NE, ldsKb[c ^ 1]);
    }

    const bf16* lKc = lK[c];
    f32x4 sacc[4] = {};
    __builtin_amdgcn_s_setprio(1);
#pragma unroll
    for (int kk = 0; kk < 2; ++kk)
#pragma unroll
      for (int j = 0; j < 4; ++j) {
        int rc = j * 16 + fr;
        bf16x8 kf = *reinterpret_cast<const bf16x8*>(
            lKc + rc * 64 + (((kg + 4 * kk) ^ (rc & 7)) << 3));
        sacc[j] = __builtin_amdgcn_mfma_f32_16x16x32_bf16(kf, qf[kk], sacc[j], 0, 0, 0);
      }
    __builtin_amdgcn_s_setprio(0);

    if (t == qt) {
      const int ql = wave * 16 + fr;
#pragma unroll
      for (int j = 0; j < 4; ++j)
#pragma unroll
        for (int r = 0; r < 4; ++r)
          if (16 * j + 4 * kg + r > ql) sacc[j][r] = -3.0e38f;
    }

    float m4 = fmaxf(fmaxf(fmaxf(sacc[0][0], sacc[0][1]), fmaxf(sacc[0][2], sacc[0][3])),
                     fmaxf(fmaxf(sacc[1][0], sacc[1][1]), fmaxf(sacc[1][2], sacc[1][3])));
    m4 = fmaxf(m4, fmaxf(fmaxf(fmaxf(sacc[2][0], sacc[2][1]), fmaxf(sacc[2][2], sacc[2][3])),
                         fmaxf(fmaxf(sacc[3][0], sacc[3][1]), fmaxf(sacc[3][2], sacc[3][3]))));
    m4 = fmaxf(m4, __shfl_xor(m4, 16));
    m4 = fmaxf(m4, __shfl_xor(m4, 32));

    if (!__all(m4 - m_ <= 8.0f)) {
      float nm = fmaxf(m_, m4);
      float corr = exp2f(m_ - nm);
      m_ = nm;
      l_ *= corr;
#pragma unroll
      for (int r = 0; r < 4; ++r) {
        float cr = __shfl(corr, kg * 4 + r);
#pragma unroll
        for (int df = 0; df < 4; ++df) oacc[df][r] *= cr;
      }
    }

    float ps = 0.f;
#pragma unroll
    for (int j = 0; j < 4; ++j) {
      float p0 = exp2f(sacc[j][0] - m_);
      float p1 = exp2f(sacc[j][1] - m_);
      float p2 = exp2f(sacc[j][2] - m_);
      float p3 = exp2f(sacc[j][3] - m_);
      ps += (p0 + p1) + (p2 + p3);
      bf16x4 pp = { (bf16)p0, (bf16)p1, (bf16)p2, (bf16)p3 };
      *reinterpret_cast<bf16x4*>(&lP[wave][fr * 68 + j * 16 + kg * 4]) = pp;
    }
    ps += __shfl_xor(ps, 16);
    ps += __shfl_xor(ps, 32);
    l_ += ps;

    __syncthreads();   // barrier B: VT(t), K(t+1) staged+visible; P visible

    __builtin_amdgcn_s_setprio(1);
#pragma unroll
    for (int ks = 0; ks < 2; ++ks) {
      bf16x8 pf = *reinterpret_cast<const bf16x8*>(&lP[wave][fr * 68 + ks * 32 + kg * 8]);
#pragma unroll
      for (int df = 0; df < 4; ++df) {
        int d = df * 16 + fr;
        bf16x8 vf = *reinterpret_cast<const bf16x8*>(
            (const bf16*)lVT + d * 64 + (((kg + 4 * ks) ^ (d & 7)) << 3));
        oacc[df] = __builtin_amdgcn_mfma_f32_16x16x32_bf16(pf, vf, oacc[df], 0, 0, 0);
      }
    }
    __builtin_amdgcn_s_setprio(0);

    __syncthreads();   // barrier A: lVT + lP free for next iter
  }

  float linv[4];
#pragma unroll
  for (int r = 0; r < 4; ++r) linv[r] = 1.0f / __shfl(l_, kg * 4 + r);
#pragma unroll
  for (int df = 0; df < 4; ++df)
#pragma unroll
    for (int r = 0; r < 4; ++r)
      Ob[(size_t)(qrow0 + kg * 4 + r) * NE + df * 16 + fr] = (bf16)(oacc[df][r] * linv[r]);
}

extern "C" void kernel_launch(void* const* d_in, const int* in_sizes, int n_in,
                              void* d_out, int out_size, void* d_ws, size_t ws_size,
                              hipStream_t stream) {
  const float* hs  = (const float*)d_in[0];
  const float* rot = (const float*)d_in[1];
  const float* qw  = (const float*)d_in[2];
  const float* kw  = (const float*)d_in[3];
  const float* vw  = (const float*)d_in[4];
  const float* ow  = (const float*)d_in[5];
  const float* obb = (const float*)d_in[6];
  float* out = (float*)d_out;

  char* ws = (char*)d_ws;
  size_t off = 0;
  bf16* hb  = (bf16*)(ws + off); off += (size_t)NM * NE * 2;
  bf16* wqb = (bf16*)(ws + off); off += (size_t)NE * NE * 2;
  bf16* wkb = (bf16*)(ws + off); off += (size_t)NE * NE * 2;
  bf16* wvb = (bf16*)(ws + off); off += (size_t)NE * NE * 2;
  bf16* wob = (bf16*)(ws + off); off += (size_t)NE * NE * 2;
  bf16* qb  = (bf16*)(ws + off); off += (size_t)NM * NE * 2;
  bf16* kb  = (bf16*)(ws + off); off += (size_t)NM * NE * 2;
  bf16* vt  = (bf16*)(ws + off); off += (size_t)NM * NE * 2;   // [bh][d][s]
  float* ct = (float*)(ws + off); off += (size_t)NS * NROT * 4;
  float* st = (float*)(ws + off); off += (size_t)NS * NROT * 4;
  bf16* aob = hb;   // hidden bf16 is dead after projections

  // fused prep (one dispatch): 4 weight-cvt slices, 4 hidden-cvt slices, tables
  PrepArgs pa = { qw, kw, vw, ow, wqb, wkb, wvb, wob, hs, hb, rot, ct, st };
  k_prep<<<dim3(NE * NE / 4 / 256, 9), dim3(256), 0, stream>>>(pa);

  // fused Q/K/VT projections + rope (256^2 tiles, fine-phase schedule)
  k_proj<<<dim3(NM / 256, NE / 256, 3), dim3(512), 0, stream>>>(
      hb, wqb, wkb, wvb, qb, kb, vt, ct, st);

  // causal flash attention (single-tile blocks, qt-descending, 1024 blocks)
  k_attn<<<dim3(8, 128), dim3(256), 0, stream>>>(qb, kb, vt, aob);

  // output projection + bias (simple single-buffered core)
  k_gemm_o<<<dim3(NM / 64, NE / 128), dim3(256), 0, stream>>>(aob, wob, out, obb);

  (void)in_sizes; (void)n_in; (void)out_size; (void)ws_size;
}